// Round 2
// baseline (4969.057 us; speedup 1.0000x reference)
//
#include <hip/hip_runtime.h>

#define Bdim 128
#define Tdim 256
#define Hdim 512
#define INdim 300
#define KXdim 320
#define NC 45
#define NTHR 256
#define FPAD 16   // ints per flag (64B cache line padding)

typedef _Float16 h16;
typedef __attribute__((ext_vector_type(8))) _Float16 half8;
typedef __attribute__((ext_vector_type(4))) float float4v;
typedef unsigned long long u64;

__device__ __forceinline__ float fast_tanh(float v) {
    float e = __expf(2.0f * v);
    return 1.0f - 2.0f / (e + 1.0f);
}

// ---- coherence-point access helpers: relaxed agent-scope atomics ----
__device__ __forceinline__ int ld_flag(const int* p) {
    return __hip_atomic_load((int*)p, __ATOMIC_RELAXED, __HIP_MEMORY_SCOPE_AGENT);
}
__device__ __forceinline__ void st_flag(int* p, int v) {
    __hip_atomic_store(p, v, __ATOMIC_RELAXED, __HIP_MEMORY_SCOPE_AGENT);
}
__device__ __forceinline__ void st_f32c(float* p, float v) {
    __hip_atomic_store(p, v, __ATOMIC_RELAXED, __HIP_MEMORY_SCOPE_AGENT);
}
// 16B fragment load as two b64 relaxed agent atomics (R4-proven)
__device__ __forceinline__ half8 ld16c(const h16* p) {
    union { u64 u[2]; half8 h; } r;
    const u64* q = (const u64*)p;
    r.u[0] = __hip_atomic_load((u64*)(q + 0), __ATOMIC_RELAXED, __HIP_MEMORY_SCOPE_AGENT);
    r.u[1] = __hip_atomic_load((u64*)(q + 1), __ATOMIC_RELAXED, __HIP_MEMORY_SCOPE_AGENT);
    return r.h;
}
__device__ __forceinline__ void st8c(h16* p, const uint* u) {
    uint* q = (uint*)p;
    __hip_atomic_store(q + 0, u[0], __ATOMIC_RELAXED, __HIP_MEMORY_SCOPE_AGENT);
    __hip_atomic_store(q + 1, u[1], __ATOMIC_RELAXED, __HIP_MEMORY_SCOPE_AGENT);
    __hip_atomic_store(q + 2, u[2], __ATOMIC_RELAXED, __HIP_MEMORY_SCOPE_AGENT);
    __hip_atomic_store(q + 3, u[3], __ATOMIC_RELAXED, __HIP_MEMORY_SCOPE_AGENT);
}

// ---------------- prep1: W0 = Wemb @ Wx0 (fp32), cb fused biases ----------------
__global__ __launch_bounds__(NTHR) void prep1_kernel(
    const float* Wemb, const float* bemb,
    const float* Wx_l2r, const float* bx_l2r, const float* bh_l2r,
    const float* Wx_r2l, const float* bx_r2l, const float* bh_r2l,
    float* W0, float* cb)
{
    int gid = blockIdx.x * NTHR + threadIdx.x;
    const int nW0 = 2 * KXdim * Hdim;
    if (gid < nW0) {
        int dir = gid / (KXdim * Hdim);
        int rem = gid % (KXdim * Hdim);
        int i = rem / Hdim, h = rem % Hdim;
        const float* Wx = dir ? Wx_r2l : Wx_l2r;
        float s = 0.f;
        if (i < INdim) {
            for (int k = 0; k < Hdim; ++k)
                s += Wemb[i * Hdim + k] * Wx[k * Hdim + h];
        }
        W0[gid] = s;
    } else {
        int idx = gid - nW0;
        if (idx < 2 * 3 * Hdim) {
            int dir = idx / (3 * Hdim);
            int l = (idx / Hdim) % 3;
            int h = idx % Hdim;
            const float* Wx = dir ? Wx_r2l : Wx_l2r;
            const float* bx = dir ? bx_r2l : bx_l2r;
            const float* bh = dir ? bh_r2l : bh_l2r;
            float s = bx[l * Hdim + h] + bh[l * Hdim + h];
            if (l == 0) {
                for (int k = 0; k < Hdim; ++k)
                    s += bemb[k] * Wx[k * Hdim + h];
            }
            cb[idx] = s;
        }
    }
}

// ---------------- pack_W: fp16 B-frag layout [u][cs16][ks32][nt2][lane64][j8] ----
__global__ __launch_bounds__(NTHR) void pack_W_kernel(
    const float* W0,
    const float* Wx_l2r, const float* Wh_l2r,
    const float* Wx_r2l, const float* Wh_r2l,
    h16* Wfrag)
{
    int e = blockIdx.x * NTHR + threadIdx.x;
    if (e >= 6 * 16 * 32 * 2 * 64 * 8) return;
    int j    = e & 7;
    int lane = (e >> 3) & 63;
    int nt   = (e >> 9) & 1;
    int ks   = (e >> 10) & 31;
    int cs   = (e >> 15) & 15;
    int u    = e >> 19;
    int dir = u / 3, l = u % 3;
    int n  = cs * 32 + nt * 16 + (lane & 15);
    int kk = ks * 32 + ((lane >> 4) * 8) + j;
    float v;
    if (kk < 512) {
        if (l == 0) {
            v = (kk < KXdim) ? W0[(dir * KXdim + kk) * Hdim + n] : 0.f;
        } else {
            const float* Wx = dir ? Wx_r2l : Wx_l2r;
            v = Wx[(l * Hdim + kk) * Hdim + n];
        }
    } else {
        const float* Wh = dir ? Wh_r2l : Wh_l2r;
        v = Wh[(l * Hdim + (kk - 512)) * Hdim + n];
    }
    Wfrag[e] = (h16)v;
}

// ---------------- pack_W0f: fp16 B-frags of W0 for zx0 kernel --------------------
__global__ __launch_bounds__(NTHR) void pack_W0f_kernel(const float* W0, h16* W0f)
{
    int e = blockIdx.x * NTHR + threadIdx.x;
    if (e >= 2 * 32 * 10 * 64 * 8) return;
    int j    = e & 7;
    int lane = (e >> 3) & 63;
    int rest = e >> 9;
    int ks   = rest % 10;
    rest /= 10;
    int nt   = rest & 31;
    int dir  = rest >> 5;
    int k = ks * 32 + ((lane >> 4) * 8) + j;
    int n = nt * 16 + (lane & 15);
    W0f[e] = (h16)W0[(dir * KXdim + k) * Hdim + n];
}

// ---------------- zx0: zx0f[dir][t][nt32][mt8][lane64][reg4] fp16 ----------------
__global__ __launch_bounds__(NTHR) void zx0_kernel(
    const float* __restrict__ x0, const float* __restrict__ x1,
    const h16* __restrict__ W0f, const float* __restrict__ cb,
    h16* __restrict__ zx0f)
{
    int bx = blockIdx.x;
    int t = bx & 255, mh = (bx >> 8) & 1, dir = bx >> 9;
    const int tid = threadIdx.x;
    __shared__ h16 xl[64 * 328];
    const float* xs = dir ? x1 : x0;
    for (int i = tid; i < 64 * 328; i += NTHR) {
        int r = i / 328, k = i - r * 328;
        int b = mh * 64 + r;
        float v = (k < INdim) ? xs[(b * Tdim + t) * INdim + k] : 0.f;
        xl[i] = (h16)v;
    }
    __syncthreads();
    int wave = tid >> 6, lane = tid & 63;
    int r15 = lane & 15, q = lane >> 4;
    for (int nt = 0; nt < 32; ++nt) {
        float4v acc = {0.f, 0.f, 0.f, 0.f};
        #pragma unroll
        for (int ks = 0; ks < 10; ++ks) {
            half8 af = *(const half8*)&xl[(wave * 16 + r15) * 328 + ks * 32 + q * 8];
            half8 bf = *(const half8*)&W0f[(((dir * 32 + nt) * 10 + ks) * 64 + lane) * 8];
            acc = __builtin_amdgcn_mfma_f32_16x16x32_f16(af, bf, acc, 0, 0, 0);
        }
        int col = nt * 16 + r15;
        float cbv = cb[(dir * 3 + 0) * Hdim + col];
        union { h16 h[4]; uint2 u2; } o;
        #pragma unroll
        for (int r = 0; r < 4; ++r) o.h[r] = (h16)(acc[r] + cbv);
        h16* dst = zx0f + (((( (size_t)dir * Tdim + t) * 32 + nt) * 8 + (mh * 4 + wave)) * 64 + lane) * 4;
        *(uint2*)dst = o.u2;
    }
}

// ---------------- zeroinit: flags only (z ring never read at t=0) ----------------
__global__ __launch_bounds__(NTHR) void zeroinit_kernel(int* zdone)
{
    int gid = blockIdx.x * NTHR + threadIdx.x;
    if (gid < 6 * 32 * FPAD) zdone[gid] = 0;
}

// ---------------- main persistent pipeline kernel --------------------------------
// 6 units * 32 blocks (mtblk2 x cs16). Block tile = 64 rows x 32 cols.
// SINGLE sync point per step: blocks publish pre-LN z (A-frag layout) + partial
// stats under one flag; consumers reconstruct h = tanh(LN(z)) during A-convert.
struct PipeArgs {
    const h16* Wfrag;    // [6][cs16][ks32][nt2][64][8]
    const h16* zx0f;     // [2][T][nt32][mt8][64][4]
    const float* cb;     // [2][3][H]
    const float* lng;    // [3][H]
    const float* lnb;    // [3][H]
    h16* zbuf;           // [6][slot4][ks16][mt8][64][8]  pre-LN z, A-frag layout
    h16* h2;             // [2][T][B][H]  post-tanh layer-2 output
    float* pstat;        // [6][slot4][B][32]  (16 x sum | 16 x sumsq)
    int* zdone;          // [6][32] padded by FPAD
};

// per-row LN coefficients from all-16-column-block partials:
// dst[row*2+0] = rstd, dst[row*2+1] = -mean*rstd
__device__ __forceinline__ void compute_mr(float* dst, const float* ps, int mtblk, int tid)
{
    if (tid < 64) {
        const u64* q = (const u64*)(ps + (mtblk * 64 + tid) * 32);
        float s = 0.f, qq = 0.f;
        #pragma unroll
        for (int i = 0; i < 8; ++i) {
            union { u64 w; float f[2]; } v;
            v.w = __hip_atomic_load((u64*)(q + i), __ATOMIC_RELAXED, __HIP_MEMORY_SCOPE_AGENT);
            s += v.f[0] + v.f[1];
        }
        #pragma unroll
        for (int i = 8; i < 16; ++i) {
            union { u64 w; float f[2]; } v;
            v.w = __hip_atomic_load((u64*)(q + i), __ATOMIC_RELAXED, __HIP_MEMORY_SCOPE_AGENT);
            qq += v.f[0] + v.f[1];
        }
        float m = s * (1.0f / Hdim);
        float var = qq * (1.0f / Hdim) - m * m;
        float rstd = rsqrtf(var + 1e-5f);
        dst[tid * 2 + 0] = rstd;
        dst[tid * 2 + 1] = -m * rstd;
    }
}

// h-frag = tanh( (z - m)*rstd * g + b )  elementwise on a half8 A-fragment
__device__ __forceinline__ half8 cvt_h(half8 zf, float A, float C,
                                       const float* g, const float* bb)
{
    union { h16 h[8]; half8 v; } o;
    #pragma unroll
    for (int j = 0; j < 8; ++j) {
        float z = (float)zf[j];
        float x = __builtin_fmaf(__builtin_fmaf(z, A, C), g[j], bb[j]);
        o.h[j] = (h16)fast_tanh(x);
    }
    return o.v;
}

__global__ __launch_bounds__(NTHR, 1) void rnn_pipe(PipeArgs a)
{
    const int blk = blockIdx.x, tid = threadIdx.x;
    const int u = blk & 7;
    if (u >= 6) return;                    // idle blocks exit
    const int widx = blk >> 3;             // 0..31
    const int mtblk = widx & 1, cs = widx >> 1;
    const int dir = u / 3, l = u % 3;
    const int wave = tid >> 6, lane = tid & 63;
    const int gmt = mtblk * 4 + wave;      // m-tile 0..7
    const int r15 = lane & 15, quad = lane >> 4;

    __shared__ h16 wlds[16384];            // 32 KB Wh frags [ks16][nt2][64][8]
    __shared__ float lnpP[2 * Hdim];       // own-layer g | b  (8 KB with lnpL)
    __shared__ float lnpL[2 * Hdim];       // lower-layer g | b
    __shared__ float mrP[128];             // per-row (rstd, -m*rstd), own unit
    __shared__ float mrL[128];             // lower unit
    __shared__ h16 lds_z[64 * 32];         // 4 KB epilogue transpose

    {   // stage Wh half (global ks 16..31) into LDS
        const h16* src = a.Wfrag + (size_t)(u * 16 + cs) * 32768 + 16384;
        for (int i = tid * 8; i < 16384; i += NTHR * 8)
            *(uint4*)&wlds[i] = *(const uint4*)&src[i];
    }
    // stage LN params
    for (int i = tid; i < Hdim; i += NTHR) {
        lnpP[i]        = a.lng[l * Hdim + i];
        lnpP[Hdim + i] = a.lnb[l * Hdim + i];
        if (l > 0) {
            lnpL[i]        = a.lng[(l - 1) * Hdim + i];
            lnpL[Hdim + i] = a.lnb[(l - 1) * Hdim + i];
        }
    }
    __syncthreads();

    const h16* wxg = a.Wfrag + (size_t)(u * 16 + cs) * 32768;   // Wx frags (L2)
    const int colbase = cs * 32 + r15;
    const float cb0v = (l > 0) ? a.cb[(dir * 3 + l) * Hdim + colbase] : 0.f;
    const float cb1v = (l > 0) ? a.cb[(dir * 3 + l) * Hdim + colbase + 16] : 0.f;

    for (int t = 0; t < Tdim; ++t) {
        // ---- wait-1: lower unit z(t) ready (l>0); upper ring throttle (l<2) ----
        for (;;) {
            int ok = 1;
            if (tid < 32) {
                if (l > 0) ok = (ld_flag(&a.zdone[((u - 1) * 32 + tid) * FPAD]) >= t + 1);
            } else if (tid >= 64 && tid < 96) {
                if (l < 2 && t >= 4) ok = (ld_flag(&a.zdone[((u + 1) * 32 + (tid - 64)) * FPAD]) >= t - 3);
            }
            if (__syncthreads_and(ok)) break;
            __builtin_amdgcn_s_sleep(2);
        }

        float4v acc0, acc1;
        if (l == 0) {
            // acc init from precomputed x-part (bias included)
            const h16* zp = a.zx0f +
                (((((size_t)dir * Tdim + t) * 32 + cs * 2) * 8 + gmt) * 64 + lane) * 4;
            union { uint2 w; h16 h[4]; } v0, v1;
            v0.w = *(const uint2*)zp;
            v1.w = *(const uint2*)(zp + 2048);
            #pragma unroll
            for (int r = 0; r < 4; ++r) { acc0[r] = (float)v0.h[r]; acc1[r] = (float)v1.h[r]; }
        } else {
            // ---- L phase (off critical path): h_lower(t) @ Wx ----
            const h16* zL = a.zbuf + (size_t)((u - 1) * 4 + (t & 3)) * 65536;
            half8 af[16];
            #pragma unroll
            for (int ks = 0; ks < 16; ++ks)
                af[ks] = ld16c(&zL[((ks * 8 + gmt) * 64 + lane) * 8]);
            compute_mr(mrL, a.pstat + (size_t)((u - 1) * 4 + (t & 3)) * 4096, mtblk, tid);
            __syncthreads();
            const float A = mrL[(wave * 16 + r15) * 2 + 0];
            const float C = mrL[(wave * 16 + r15) * 2 + 1];
            acc0 = (float4v){0.f, 0.f, 0.f, 0.f};
            acc1 = (float4v){0.f, 0.f, 0.f, 0.f};
            #pragma unroll
            for (int ks = 0; ks < 16; ++ks) {
                int k0 = ks * 32 + quad * 8;
                half8 hf = cvt_h(af[ks], A, C, &lnpL[k0], &lnpL[Hdim + k0]);
                half8 bx0 = *(const half8*)&wxg[((ks * 2 + 0) * 64 + lane) * 8];
                half8 bx1 = *(const half8*)&wxg[((ks * 2 + 1) * 64 + lane) * 8];
                acc0 = __builtin_amdgcn_mfma_f32_16x16x32_f16(hf, bx0, acc0, 0, 0, 0);
                acc1 = __builtin_amdgcn_mfma_f32_16x16x32_f16(hf, bx1, acc1, 0, 0, 0);
            }
        }

        // ---- wait-2: own unit z(t-1)+stats ready (trivially true at t=0) ----
        for (;;) {
            int ok = 1;
            if (tid < 32) ok = (ld_flag(&a.zdone[(u * 32 + tid) * FPAD]) >= t);
            if (__syncthreads_and(ok)) break;
            __builtin_amdgcn_s_sleep(2);
        }
        if (t > 0) {
            // ---- P phase: h_prev(t-1) @ Wh, reconstructing h on the fly ----
            const h16* zP = a.zbuf + (size_t)(u * 4 + ((t + 3) & 3)) * 65536;
            half8 af[16];
            #pragma unroll
            for (int ks = 0; ks < 16; ++ks)
                af[ks] = ld16c(&zP[((ks * 8 + gmt) * 64 + lane) * 8]);
            compute_mr(mrP, a.pstat + (size_t)(u * 4 + ((t + 3) & 3)) * 4096, mtblk, tid);
            __syncthreads();
            const float A = mrP[(wave * 16 + r15) * 2 + 0];
            const float C = mrP[(wave * 16 + r15) * 2 + 1];
            #pragma unroll
            for (int ks = 0; ks < 16; ++ks) {
                int k0 = ks * 32 + quad * 8;
                half8 hf = cvt_h(af[ks], A, C, &lnpP[k0], &lnpP[Hdim + k0]);
                if (l == 2 && ks == cs) {
                    // free h2(t-1) write: this convert IS tanh(LN(z(t-1)))
                    union { half8 v; uint4 q; } w; w.v = hf;
                    *(uint4*)&a.h2[(((size_t)dir * Tdim + (t - 1)) * Bdim + gmt * 16 + r15) * Hdim + k0] = w.q;
                }
                half8 bh0 = *(const half8*)&wlds[((ks * 2 + 0) * 64 + lane) * 8];
                half8 bh1 = *(const half8*)&wlds[((ks * 2 + 1) * 64 + lane) * 8];
                acc0 = __builtin_amdgcn_mfma_f32_16x16x32_f16(hf, bh0, acc0, 0, 0, 0);
                acc1 = __builtin_amdgcn_mfma_f32_16x16x32_f16(hf, bh1, acc1, 0, 0, 0);
            }
        }

        // ---- epilogue: bias, per-row partial stats, publish z + stats + flag ----
        float z0[4], z1[4];
        #pragma unroll
        for (int r = 0; r < 4; ++r) {
            z0[r] = acc0[r] + cb0v;
            z1[r] = acc1[r] + cb1v;
            float s = z0[r] + z1[r];
            float q2 = z0[r] * z0[r] + z1[r] * z1[r];
            s += __shfl_xor(s, 1);  q2 += __shfl_xor(q2, 1);
            s += __shfl_xor(s, 2);  q2 += __shfl_xor(q2, 2);
            s += __shfl_xor(s, 4);  q2 += __shfl_xor(q2, 4);
            s += __shfl_xor(s, 8);  q2 += __shfl_xor(q2, 8);
            if (r15 == 0) {
                int b = mtblk * 64 + wave * 16 + quad * 4 + r;
                float* pr = a.pstat + (size_t)(u * 4 + (t & 3)) * 4096 + b * 32;
                st_f32c(pr + cs, s);
                st_f32c(pr + 16 + cs, q2);
            }
        }
        // z tile (fp16) -> LDS transpose for wide frag stores
        #pragma unroll
        for (int r = 0; r < 4; ++r) {
            int lrow = wave * 16 + quad * 4 + r;
            lds_z[lrow * 32 + r15]      = (h16)z0[r];
            lds_z[lrow * 32 + 16 + r15] = (h16)z1[r];
        }
        __syncthreads();
        {
            int b_l = tid >> 2, c0 = (tid & 3) * 8;
            union { h16 h[8]; uint u4[4]; } o;
            const h16* srcz = &lds_z[b_l * 32 + c0];
            #pragma unroll
            for (int j = 0; j < 8; ++j) o.h[j] = srcz[j];
            int mt = mtblk * 4 + (b_l >> 4);
            int lane2 = (b_l & 15) | ((tid & 3) << 4);
            h16* dst = a.zbuf + (size_t)(u * 4 + (t & 3)) * 65536 +
                       ((size_t)((cs * 8 + mt) * 64 + lane2)) * 8;
            st8c(dst, o.u4);
        }
        __syncthreads();                    // drains vmcnt -> z + stats visible
        if (tid == 0) st_flag(&a.zdone[(u * 32 + widx) * FPAD], t + 1);
    }

    // ---- tail: l==2 writes h2(T-1) (stats for step T-1 now published) ----
    if (l == 2) {
        for (;;) {
            int ok = 1;
            if (tid < 32) ok = (ld_flag(&a.zdone[(u * 32 + tid) * FPAD]) >= Tdim);
            if (__syncthreads_and(ok)) break;
            __builtin_amdgcn_s_sleep(2);
        }
        compute_mr(mrP, a.pstat + (size_t)(u * 4 + 3) * 4096, mtblk, tid);
        __syncthreads();
        const h16* zP = a.zbuf + (size_t)(u * 4 + 3) * 65536;
        const float A = mrP[(wave * 16 + r15) * 2 + 0];
        const float C = mrP[(wave * 16 + r15) * 2 + 1];
        int ks = cs;
        int k0 = ks * 32 + quad * 8;
        half8 zf = ld16c(&zP[((ks * 8 + gmt) * 64 + lane) * 8]);
        half8 hf = cvt_h(zf, A, C, &lnpP[k0], &lnpP[Hdim + k0]);
        union { half8 v; uint4 q; } w; w.v = hf;
        *(uint4*)&a.h2[(((size_t)dir * Tdim + (Tdim - 1)) * Bdim + gmt * 16 + r15) * Hdim + k0] = w.q;
    }
}

// ---------------- FC: logits = [h_l2r ; gather(h_r2l)] @ W_fc + b_fc -------------
__global__ __launch_bounds__(NTHR) void fc_kernel(
    const h16* __restrict__ h2, const int* __restrict__ pad,
    const float* __restrict__ Wfc, const float* __restrict__ bfc,
    float* __restrict__ out)
{
    __shared__ float sA[64 * 68];
    __shared__ float sB[64 * 48];
    const int blk = blockIdx.x, tid = threadIdx.x;
    const int b = blk >> 2;
    const int j0 = (blk & 3) * 64;
    const int p = pad[b];
    const int rg = tid >> 4;
    const int c0 = (tid & 15) * 3;
    float acc[4][3] = {};

    for (int k0 = 0; k0 < 2 * Hdim; k0 += 64) {
        {
            int rr = tid >> 2;
            int kp = (tid & 3) * 16;
            int j = j0 + rr;
            const h16* src;
            if (k0 < Hdim) {
                src = h2 + (((size_t)0 * Tdim + j) * Bdim + b) * Hdim + k0 + kp;
            } else {
                int idx = (j < p) ? (p - j - 1) : j;
                src = h2 + (((size_t)1 * Tdim + idx) * Bdim + b) * Hdim + (k0 - Hdim) + kp;
            }
            union { uint4 u4; h16 h[8]; } w0, w1;
            w0.u4 = *(const uint4*)src;
            w1.u4 = *(const uint4*)(src + 8);
            #pragma unroll
            for (int i = 0; i < 8; ++i) {
                sA[rr * 68 + kp + i]     = (float)w0.h[i];
                sA[rr * 68 + kp + 8 + i] = (float)w1.h[i];
            }
        }
        for (int e = tid; e < 64 * 48; e += NTHR) {
            int kk = e / 48, c = e - kk * 48;
            sB[e] = (c < NC) ? Wfc[(k0 + kk) * NC + c] : 0.f;
        }
        __syncthreads();
        for (int kk = 0; kk < 64; ++kk) {
            float b0 = sB[kk * 48 + c0 + 0];
            float b1 = sB[kk * 48 + c0 + 1];
            float b2 = sB[kk * 48 + c0 + 2];
            #pragma unroll
            for (int i = 0; i < 4; ++i) {
                float av = sA[(rg * 4 + i) * 68 + kk];
                acc[i][0] += av * b0; acc[i][1] += av * b1; acc[i][2] += av * b2;
            }
        }
        __syncthreads();
    }
    #pragma unroll
    for (int i = 0; i < 4; ++i) {
        int r = blk * 64 + rg * 4 + i;
        #pragma unroll
        for (int jj = 0; jj < 3; ++jj) {
            int c = c0 + jj;
            if (c < NC) out[r * NC + c] = acc[i][jj] + bfc[c];
        }
    }
}

extern "C" void kernel_launch(void* const* d_in, const int* in_sizes, int n_in,
                              void* d_out, int out_size, void* d_ws, size_t ws_size,
                              hipStream_t stream) {
    const float* x      = (const float*)d_in[0];
    const float* rx     = (const float*)d_in[1];
    const int*   pad    = (const int*)d_in[2];
    const float* Wemb   = (const float*)d_in[4];
    const float* bemb   = (const float*)d_in[5];
    const float* Wx_l2r = (const float*)d_in[6];
    const float* bx_l2r = (const float*)d_in[7];
    const float* Wh_l2r = (const float*)d_in[8];
    const float* bh_l2r = (const float*)d_in[9];
    const float* Wx_r2l = (const float*)d_in[10];
    const float* bx_r2l = (const float*)d_in[11];
    const float* Wh_r2l = (const float*)d_in[12];
    const float* bh_r2l = (const float*)d_in[13];
    const float* lng    = (const float*)d_in[14];
    const float* lnb    = (const float*)d_in[15];
    const float* Wfc    = (const float*)d_in[16];
    const float* bfc    = (const float*)d_in[17];

    char* base = (char*)d_ws;
    size_t off = 0;
    auto alloc = [&](size_t bytes) { char* p = base + off; off += (bytes + 255) & ~(size_t)255; return p; };
    h16*   zx0f  = (h16*)  alloc((size_t)2 * Tdim * 32 * 8 * 64 * 4 * 2);      // 67 MB
    h16*   h2    = (h16*)  alloc((size_t)2 * Tdim * Bdim * Hdim * 2);          // 67 MB
    h16*   Wfrag = (h16*)  alloc((size_t)6 * 16 * 32768 * 2);                  // 6.3 MB
    h16*   W0f   = (h16*)  alloc((size_t)2 * 32 * 10 * 64 * 8 * 2);            // 0.66 MB
    h16*   zbuf  = (h16*)  alloc((size_t)6 * 4 * 65536 * 2);                   // 3.1 MB
    float* pstat = (float*)alloc((size_t)6 * 4 * Bdim * 32 * 4);               // 0.39 MB
    float* W0    = (float*)alloc((size_t)2 * KXdim * Hdim * 4);
    float* cb    = (float*)alloc((size_t)2 * 3 * Hdim * 4);
    int*   zdone = (int*)  alloc((size_t)6 * 32 * FPAD * 4);

    prep1_kernel<<<(2 * KXdim * Hdim + 2 * 3 * Hdim) / NTHR, NTHR, 0, stream>>>(
        Wemb, bemb, Wx_l2r, bx_l2r, bh_l2r, Wx_r2l, bx_r2l, bh_r2l, W0, cb);

    pack_W_kernel<<<(6 * 16 * 32 * 2 * 64 * 8) / NTHR, NTHR, 0, stream>>>(
        W0, Wx_l2r, Wh_l2r, Wx_r2l, Wh_r2l, Wfrag);

    pack_W0f_kernel<<<(2 * 32 * 10 * 64 * 8) / NTHR, NTHR, 0, stream>>>(W0, W0f);

    zx0_kernel<<<1024, NTHR, 0, stream>>>(x, rx, W0f, cb, zx0f);

    zeroinit_kernel<<<(6 * 32 * FPAD + NTHR - 1) / NTHR, NTHR, 0, stream>>>(zdone);

    PipeArgs a;
    a.Wfrag = Wfrag; a.zx0f = zx0f; a.cb = cb; a.lng = lng; a.lnb = lnb;
    a.zbuf = zbuf; a.h2 = h2; a.pstat = pstat; a.zdone = zdone;
    void* kargs[] = { &a };
    hipLaunchCooperativeKernel((void*)rnn_pipe, dim3(256), dim3(NTHR), kargs, 0, stream);

    fc_kernel<<<(Bdim * Tdim) / 64, NTHR, 0, stream>>>(h2, pad, Wfc, bfc, (float*)d_out);
}

// Round 4
// 3597.452 us; speedup vs baseline: 1.3813x; 1.3813x over previous
//
#include <hip/hip_runtime.h>

#define Bdim 128
#define Tdim 256
#define Hdim 512
#define INdim 300
#define KXdim 320
#define NC 45
#define NTHR 256
#define FPAD 16   // ints per flag (64B cache line padding)

typedef _Float16 h16;
typedef __attribute__((ext_vector_type(8))) _Float16 half8;
typedef __attribute__((ext_vector_type(4))) float float4v;
typedef unsigned long long u64;

// ---- coherence-point access helpers: agent-scope atomics ----
__device__ __forceinline__ int ld_flag(const int* p) {
    return __hip_atomic_load((int*)p, __ATOMIC_RELAXED, __HIP_MEMORY_SCOPE_AGENT);
}
// RELEASE publish: orders all prior (data) stores before the flag at the
// coherence point -- do not rely on __syncthreads' vmcnt drain alone.
__device__ __forceinline__ void st_flag_rel(int* p, int v) {
    __hip_atomic_store(p, v, __ATOMIC_RELEASE, __HIP_MEMORY_SCOPE_AGENT);
}
// 16B fragment load as two b64 relaxed agent atomics
__device__ __forceinline__ half8 ld16c(const h16* p) {
    union { u64 u[2]; half8 h; } r;
    const u64* q = (const u64*)p;
    r.u[0] = __hip_atomic_load((u64*)(q + 0), __ATOMIC_RELAXED, __HIP_MEMORY_SCOPE_AGENT);
    r.u[1] = __hip_atomic_load((u64*)(q + 1), __ATOMIC_RELAXED, __HIP_MEMORY_SCOPE_AGENT);
    return r.h;
}
__device__ __forceinline__ float4v ld16cf(const float* p) {
    union { u64 u[2]; float4v f; } r;
    const u64* q = (const u64*)p;
    r.u[0] = __hip_atomic_load((u64*)(q + 0), __ATOMIC_RELAXED, __HIP_MEMORY_SCOPE_AGENT);
    r.u[1] = __hip_atomic_load((u64*)(q + 1), __ATOMIC_RELAXED, __HIP_MEMORY_SCOPE_AGENT);
    return r.f;
}
__device__ __forceinline__ void st16cf(float* p, float4v v) {
    union { float4v f; u64 u[2]; } w; w.f = v;
    u64* q = (u64*)p;
    __hip_atomic_store(q + 0, w.u[0], __ATOMIC_RELAXED, __HIP_MEMORY_SCOPE_AGENT);
    __hip_atomic_store(q + 1, w.u[1], __ATOMIC_RELAXED, __HIP_MEMORY_SCOPE_AGENT);
}
__device__ __forceinline__ void st8c(h16* p, const uint* u) {
    uint* q = (uint*)p;
    __hip_atomic_store(q + 0, u[0], __ATOMIC_RELAXED, __HIP_MEMORY_SCOPE_AGENT);
    __hip_atomic_store(q + 1, u[1], __ATOMIC_RELAXED, __HIP_MEMORY_SCOPE_AGENT);
    __hip_atomic_store(q + 2, u[2], __ATOMIC_RELAXED, __HIP_MEMORY_SCOPE_AGENT);
    __hip_atomic_store(q + 3, u[3], __ATOMIC_RELAXED, __HIP_MEMORY_SCOPE_AGENT);
}

// h = tanh((z*A + C)*g + b), with g2=2g, b2=2b pre-staged.
// tanh(x) = 1 - 2/(e^{2x}+1); __expf + __fdividef -> v_exp + v_rcp.
__device__ __forceinline__ half8 cvt_tanh(half8 zf, float A, float C,
                                          const float* g2, const float* b2)
{
    union { h16 h[8]; half8 v; } o;
    #pragma unroll
    for (int j = 0; j < 8; ++j) {
        float z = (float)zf[j];
        float x2 = __builtin_fmaf(__builtin_fmaf(z, A, C), g2[j], b2[j]); // = 2*(LN affine)
        float E = __expf(x2);
        o.h[j] = (h16)(1.0f - __fdividef(2.0f, E + 1.0f));
    }
    return o.v;
}

// ---------------- prep1: W0 = Wemb @ Wx0 (fp32), cb fused biases ----------------
__global__ __launch_bounds__(NTHR) void prep1_kernel(
    const float* Wemb, const float* bemb,
    const float* Wx_l2r, const float* bx_l2r, const float* bh_l2r,
    const float* Wx_r2l, const float* bx_r2l, const float* bh_r2l,
    float* W0, float* cb)
{
    int gid = blockIdx.x * NTHR + threadIdx.x;
    const int nW0 = 2 * KXdim * Hdim;
    if (gid < nW0) {
        int dir = gid / (KXdim * Hdim);
        int rem = gid % (KXdim * Hdim);
        int i = rem / Hdim, h = rem % Hdim;
        const float* Wx = dir ? Wx_r2l : Wx_l2r;
        float s = 0.f;
        if (i < INdim) {
            for (int k = 0; k < Hdim; ++k)
                s += Wemb[i * Hdim + k] * Wx[k * Hdim + h];
        }
        W0[gid] = s;
    } else {
        int idx = gid - nW0;
        if (idx < 2 * 3 * Hdim) {
            int dir = idx / (3 * Hdim);
            int l = (idx / Hdim) % 3;
            int h = idx % Hdim;
            const float* Wx = dir ? Wx_r2l : Wx_l2r;
            const float* bx = dir ? bx_r2l : bx_l2r;
            const float* bh = dir ? bh_r2l : bh_l2r;
            float s = bx[l * Hdim + h] + bh[l * Hdim + h];
            if (l == 0) {
                for (int k = 0; k < Hdim; ++k)
                    s += bemb[k] * Wx[k * Hdim + h];
            }
            cb[idx] = s;
        }
    }
}

// ---------------- pack_W: fp16 B-frag layout [u][cs16][ks32][nt2][lane64][j8] ----
__global__ __launch_bounds__(NTHR) void pack_W_kernel(
    const float* W0,
    const float* Wx_l2r, const float* Wh_l2r,
    const float* Wx_r2l, const float* Wh_r2l,
    h16* Wfrag)
{
    int e = blockIdx.x * NTHR + threadIdx.x;
    if (e >= 6 * 16 * 32 * 2 * 64 * 8) return;
    int j    = e & 7;
    int lane = (e >> 3) & 63;
    int nt   = (e >> 9) & 1;
    int ks   = (e >> 10) & 31;
    int cs   = (e >> 15) & 15;
    int u    = e >> 19;
    int dir = u / 3, l = u % 3;
    int n  = cs * 32 + nt * 16 + (lane & 15);
    int kk = ks * 32 + ((lane >> 4) * 8) + j;
    float v;
    if (kk < 512) {
        if (l == 0) {
            v = (kk < KXdim) ? W0[(dir * KXdim + kk) * Hdim + n] : 0.f;
        } else {
            const float* Wx = dir ? Wx_r2l : Wx_l2r;
            v = Wx[(l * Hdim + kk) * Hdim + n];
        }
    } else {
        const float* Wh = dir ? Wh_r2l : Wh_l2r;
        v = Wh[(l * Hdim + (kk - 512)) * Hdim + n];
    }
    Wfrag[e] = (h16)v;
}

// ---------------- pack_W0f: fp16 B-frags of W0 for zx0 kernel --------------------
__global__ __launch_bounds__(NTHR) void pack_W0f_kernel(const float* W0, h16* W0f)
{
    int e = blockIdx.x * NTHR + threadIdx.x;
    if (e >= 2 * 32 * 10 * 64 * 8) return;
    int j    = e & 7;
    int lane = (e >> 3) & 63;
    int rest = e >> 9;
    int ks   = rest % 10;
    rest /= 10;
    int nt   = rest & 31;
    int dir  = rest >> 5;
    int k = ks * 32 + ((lane >> 4) * 8) + j;
    int n = nt * 16 + (lane & 15);
    W0f[e] = (h16)W0[(dir * KXdim + k) * Hdim + n];
}

// ---------------- zx0: zx0f[dir][t][nt32][mt8][lane64][reg4] fp16 ----------------
__global__ __launch_bounds__(NTHR) void zx0_kernel(
    const float* __restrict__ x0, const float* __restrict__ x1,
    const h16* __restrict__ W0f, const float* __restrict__ cb,
    h16* __restrict__ zx0f)
{
    int bx = blockIdx.x;
    int t = bx & 255, mh = (bx >> 8) & 1, dir = bx >> 9;
    const int tid = threadIdx.x;
    __shared__ h16 xl[64 * 328];
    const float* xs = dir ? x1 : x0;
    for (int i = tid; i < 64 * 328; i += NTHR) {
        int r = i / 328, k = i - r * 328;
        int b = mh * 64 + r;
        float v = (k < INdim) ? xs[(b * Tdim + t) * INdim + k] : 0.f;
        xl[i] = (h16)v;
    }
    __syncthreads();
    int wave = tid >> 6, lane = tid & 63;
    int r15 = lane & 15, q = lane >> 4;
    for (int nt = 0; nt < 32; ++nt) {
        float4v acc = {0.f, 0.f, 0.f, 0.f};
        #pragma unroll
        for (int ks = 0; ks < 10; ++ks) {
            half8 af = *(const half8*)&xl[(wave * 16 + r15) * 328 + ks * 32 + q * 8];
            half8 bf = *(const half8*)&W0f[(((dir * 32 + nt) * 10 + ks) * 64 + lane) * 8];
            acc = __builtin_amdgcn_mfma_f32_16x16x32_f16(af, bf, acc, 0, 0, 0);
        }
        int col = nt * 16 + r15;
        float cbv = cb[(dir * 3 + 0) * Hdim + col];
        union { h16 h[4]; uint2 u2; } o;
        #pragma unroll
        for (int r = 0; r < 4; ++r) o.h[r] = (h16)(acc[r] + cbv);
        h16* dst = zx0f + (((( (size_t)dir * Tdim + t) * 32 + nt) * 8 + (mh * 4 + wave)) * 64 + lane) * 4;
        *(uint2*)dst = o.u2;
    }
}

// ---------------- zeroinit: flags ------------------------------------------------
__global__ __launch_bounds__(NTHR) void zeroinit_kernel(int* zdoneH, int* zxdone)
{
    int gid = blockIdx.x * NTHR + threadIdx.x;
    if (gid < 6 * 32 * FPAD) zdoneH[gid] = 0;
    if (gid < 6 * 16 * FPAD) zxdone[gid] = 0;
}

// ---------------- main persistent pipeline kernel --------------------------------
struct PipeArgs {
    const h16* Wfrag;    // [6][cs16][ks32][nt2][64][8]
    const h16* zx0f;     // [2][T][nt32][mt8][64][4] fp16
    const float* cb;     // [2][3][H]
    const float* lng;    // [3][H]
    const float* lnb;    // [3][H]
    h16* zbuf;           // [6][slot4][ks16][mt8][64][8]  pre-LN z, A-frag layout
    float* zxbuf;        // [6][slot4][nt32][mt8][64][4]  f32 C-frags (x-part + cb)
    h16* h2;             // [2][T][B][H]
    int* zdoneH;         // [6][32] * FPAD
    int* zxdone;         // [6][16] * FPAD
};

__global__ __launch_bounds__(NTHR, 1) void rnn_pipe(PipeArgs a)
{
    const int blk = blockIdx.x, tid = threadIdx.x;
    const int wave = tid >> 6, lane = tid & 63;
    const int r15 = lane & 15, quad = lane >> 4;
    const int u7 = blk & 7;

    __shared__ h16 wlds[32768];        // H: 32KB Wh frags; X: 64KB Wx frags
    __shared__ float g2s[Hdim], b2s[Hdim];
    __shared__ h16 lds_z[64 * 32];

    if (u7 < 6) {
        // ================= H role =================
        const int u = u7, widx = blk >> 3;
        const int mtblk = widx & 1, cs = widx >> 1;
        const int dir = u / 3, l = u % 3;
        const int gmt = mtblk * 4 + wave;

        {   // stage Wh half (global ks 16..31) into LDS
            const h16* src = a.Wfrag + (size_t)(u * 16 + cs) * 32768 + 16384;
            for (int i = tid * 8; i < 16384; i += NTHR * 8)
                *(uint4*)&wlds[i] = *(const uint4*)&src[i];
        }
        for (int i = tid; i < Hdim; i += NTHR) {
            g2s[i] = 2.0f * a.lng[l * Hdim + i];
            b2s[i] = 2.0f * a.lnb[l * Hdim + i];
        }
        __syncthreads();

        const int upperX = (u + 1) * 16 + mtblk * 8;   // valid only when l<2
        const int zxflag = (u * 16 + mtblk * 8 + (cs >> 1)) * FPAD;  // l>0 only

        for (int t = 0; t < Tdim; ++t) {
            // ---- wait-A: own peers z(t-1); throttle: upper X consumed z(t-4) ----
            for (;;) {
                int ok = 1;
                if (tid < 32) {
                    if (t > 0) ok = (ld_flag(&a.zdoneH[(u * 32 + tid) * FPAD]) >= t);
                } else if (tid >= 64 && tid < 72) {
                    if (l < 2 && t >= 4)
                        ok = (ld_flag(&a.zxdone[(upperX + tid - 64) * FPAD]) >= t - 3);
                }
                if (__syncthreads_and(ok)) break;
                __builtin_amdgcn_s_sleep(1);
            }
            asm volatile("" ::: "memory");

            float4v acc0 = {0.f, 0.f, 0.f, 0.f};
            float4v acc1 = {0.f, 0.f, 0.f, 0.f};
            if (t > 0) {
                const h16* zP = a.zbuf + (size_t)(u * 4 + ((t + 3) & 3)) * 65536;
                half8 af[16];
                #pragma unroll
                for (int ks = 0; ks < 16; ++ks)
                    af[ks] = ld16c(&zP[((ks * 8 + gmt) * 64 + lane) * 8]);
                // ---- local LN stats (full row spread over quad lanes) ----
                float sm = 0.f, sq = 0.f;
                #pragma unroll
                for (int ks = 0; ks < 16; ++ks) {
                    #pragma unroll
                    for (int j = 0; j < 8; ++j) {
                        float v = (float)af[ks][j];
                        sm += v; sq = __builtin_fmaf(v, v, sq);
                    }
                }
                sm += __shfl_xor(sm, 16); sq += __shfl_xor(sq, 16);
                sm += __shfl_xor(sm, 32); sq += __shfl_xor(sq, 32);
                float m = sm * (1.0f / Hdim);
                float var = sq * (1.0f / Hdim) - m * m;
                float rstd = rsqrtf(var + 1e-5f);
                float A = rstd, Cc = -m * rstd;
                // ---- convert + Wh MFMA ----
                #pragma unroll
                for (int ks = 0; ks < 16; ++ks) {
                    int k0 = ks * 32 + quad * 8;
                    half8 hf = cvt_tanh(af[ks], A, Cc, &g2s[k0], &b2s[k0]);
                    if (l == 2 && ks == cs) {
                        union { half8 v; uint4 q; } w; w.v = hf;
                        *(uint4*)&a.h2[(((size_t)dir * Tdim + (t - 1)) * Bdim + gmt * 16 + r15) * Hdim + k0] = w.q;
                    }
                    half8 bh0 = *(const half8*)&wlds[((ks * 2 + 0) * 64 + lane) * 8];
                    half8 bh1 = *(const half8*)&wlds[((ks * 2 + 1) * 64 + lane) * 8];
                    acc0 = __builtin_amdgcn_mfma_f32_16x16x32_f16(hf, bh0, acc0, 0, 0, 0);
                    acc1 = __builtin_amdgcn_mfma_f32_16x16x32_f16(hf, bh1, acc1, 0, 0, 0);
                }
            }

            // ---- wait-B: zx(t) from X-team (l>0) or zx0f (l==0) ----
            if (l > 0) {
                for (;;) {
                    int ok = 1;
                    if (tid < 32) ok = (ld_flag(&a.zxdone[zxflag]) >= t + 1);
                    if (__syncthreads_and(ok)) break;
                    __builtin_amdgcn_s_sleep(1);
                }
                asm volatile("" ::: "memory");
                const float* zx = a.zxbuf +
                    (((size_t)(u * 4 + (t & 3)) * 32 + cs * 2) * 8 + gmt) * 256 + lane * 4;
                float4v x0 = ld16cf(zx);
                float4v x1 = ld16cf(zx + 2048);
                acc0 += x0; acc1 += x1;
            } else {
                const h16* zp = a.zx0f +
                    (((((size_t)dir * Tdim + t) * 32 + cs * 2) * 8 + gmt) * 64 + lane) * 4;
                union { uint2 w; h16 h[4]; } v0, v1;
                v0.w = *(const uint2*)zp;
                v1.w = *(const uint2*)(zp + 2048);
                #pragma unroll
                for (int r = 0; r < 4; ++r) { acc0[r] += (float)v0.h[r]; acc1[r] += (float)v1.h[r]; }
            }

            // ---- pack z-frags (LDS transpose) + publish under one flag ----
            #pragma unroll
            for (int r = 0; r < 4; ++r) {
                int lrow = wave * 16 + quad * 4 + r;
                lds_z[lrow * 32 + r15]      = (h16)acc0[r];
                lds_z[lrow * 32 + 16 + r15] = (h16)acc1[r];
            }
            __syncthreads();
            {
                int b_l = tid >> 2, c0 = (tid & 3) * 8;
                union { h16 h[8]; uint u4[4]; } o;
                const h16* srcz = &lds_z[b_l * 32 + c0];
                #pragma unroll
                for (int j = 0; j < 8; ++j) o.h[j] = srcz[j];
                int mt = mtblk * 4 + (b_l >> 4);
                int lane2 = (b_l & 15) | ((tid & 3) << 4);
                h16* dst = a.zbuf + (size_t)(u * 4 + (t & 3)) * 65536 +
                           ((size_t)((cs * 8 + mt) * 64 + lane2)) * 8;
                st8c(dst, o.u4);
            }
            __syncthreads();
            if (tid == 0) st_flag_rel(&a.zdoneH[(u * 32 + widx) * FPAD], t + 1);
        }

        // ---- tail: l==2 writes h2(T-1) ----
        if (l == 2) {
            for (;;) {
                int ok = 1;
                if (tid < 32) ok = (ld_flag(&a.zdoneH[(u * 32 + tid) * FPAD]) >= Tdim);
                if (__syncthreads_and(ok)) break;
                __builtin_amdgcn_s_sleep(1);
            }
            asm volatile("" ::: "memory");
            const h16* zP = a.zbuf + (size_t)(u * 4 + 3) * 65536;
            half8 af[16];
            #pragma unroll
            for (int ks = 0; ks < 16; ++ks)
                af[ks] = ld16c(&zP[((ks * 8 + gmt) * 64 + lane) * 8]);
            float sm = 0.f, sq = 0.f;
            #pragma unroll
            for (int ks = 0; ks < 16; ++ks) {
                #pragma unroll
                for (int j = 0; j < 8; ++j) {
                    float v = (float)af[ks][j];
                    sm += v; sq = __builtin_fmaf(v, v, sq);
                }
            }
            sm += __shfl_xor(sm, 16); sq += __shfl_xor(sq, 16);
            sm += __shfl_xor(sm, 32); sq += __shfl_xor(sq, 32);
            float m = sm * (1.0f / Hdim);
            float var = sq * (1.0f / Hdim) - m * m;
            float rstd = rsqrtf(var + 1e-5f);
            int k0 = cs * 32 + quad * 8;
            half8 hf = cvt_tanh(af[cs], rstd, -m * rstd, &g2s[k0], &b2s[k0]);
            union { half8 v; uint4 q; } w; w.v = hf;
            *(uint4*)&a.h2[(((size_t)dir * Tdim + (Tdim - 1)) * Bdim + gmt * 16 + r15) * Hdim + k0] = w.q;
        }
    } else {
        // ================= X role =================
        const int xraw = (blk >> 3) * 2 + (u7 - 6);        // 0..63
        const int xui = xraw >> 4;                          // 0..3
        const int xu = (xui < 2) ? (xui + 1) : (xui + 2);   // {1,2,4,5}
        const int sub = xraw & 15;
        const int mtblk = sub >> 3, cx = sub & 7;
        const int dir = xu / 3, l = xu % 3;
        const int lowU = xu - 1;
        const int gmt = mtblk * 4 + wave;

        {   // stage Wx (cols cx*64..+63, ks 0..15) -> wlds [ks16][n4][64][8]
            for (int f = tid; f < 4096; f += NTHR) {
                int ks = f >> 8;
                int rr = f & 255;
                int n  = rr >> 6;
                int li = rr & 63;
                int cs2 = 2 * cx + (n >> 1);
                int nt  = n & 1;
                const h16* src = a.Wfrag +
                    ((((size_t)(xu * 16 + cs2) * 32 + ks) * 2 + nt) * 64 + li) * 8;
                *(uint4*)&wlds[(size_t)f * 8] = *(const uint4*)src;
            }
        }
        for (int i = tid; i < Hdim; i += NTHR) {
            g2s[i] = 2.0f * a.lng[(l - 1) * Hdim + i];   // LOWER layer params
            b2s[i] = 2.0f * a.lnb[(l - 1) * Hdim + i];
        }
        __syncthreads();

        float cbv[4];
        #pragma unroll
        for (int n = 0; n < 4; ++n)
            cbv[n] = a.cb[(dir * 3 + l) * Hdim + cx * 64 + n * 16 + r15];

        const int myflag = (xu * 16 + mtblk * 8 + cx) * FPAD;

        for (int t = 0; t < Tdim; ++t) {
            // ---- wait: lower z(t); throttle: own-H consumers past zx(t-4) ----
            for (;;) {
                int ok = 1;
                if (tid < 32) {
                    ok = (ld_flag(&a.zdoneH[(lowU * 32 + tid) * FPAD]) >= t + 1);
                } else if (tid >= 64 && tid < 66) {
                    if (t >= 4) {
                        int wc = 4 * cx + mtblk + (tid - 64) * 2;
                        ok = (ld_flag(&a.zdoneH[(xu * 32 + wc) * FPAD]) >= t - 3);
                    }
                }
                if (__syncthreads_and(ok)) break;
                __builtin_amdgcn_s_sleep(1);
            }
            asm volatile("" ::: "memory");

            const h16* zP = a.zbuf + (size_t)(lowU * 4 + (t & 3)) * 65536;
            half8 af[16];
            #pragma unroll
            for (int ks = 0; ks < 16; ++ks)
                af[ks] = ld16c(&zP[((ks * 8 + gmt) * 64 + lane) * 8]);
            float sm = 0.f, sq = 0.f;
            #pragma unroll
            for (int ks = 0; ks < 16; ++ks) {
                #pragma unroll
                for (int j = 0; j < 8; ++j) {
                    float v = (float)af[ks][j];
                    sm += v; sq = __builtin_fmaf(v, v, sq);
                }
            }
            sm += __shfl_xor(sm, 16); sq += __shfl_xor(sq, 16);
            sm += __shfl_xor(sm, 32); sq += __shfl_xor(sq, 32);
            float m = sm * (1.0f / Hdim);
            float var = sq * (1.0f / Hdim) - m * m;
            float rstd = rsqrtf(var + 1e-5f);
            float A = rstd, Cc = -m * rstd;

            float4v acc[4];
            #pragma unroll
            for (int n = 0; n < 4; ++n) acc[n] = (float4v){0.f, 0.f, 0.f, 0.f};
            #pragma unroll
            for (int ks = 0; ks < 16; ++ks) {
                int k0 = ks * 32 + quad * 8;
                half8 hf = cvt_tanh(af[ks], A, Cc, &g2s[k0], &b2s[k0]);
                #pragma unroll
                for (int n = 0; n < 4; ++n) {
                    half8 bf = *(const half8*)&wlds[((ks * 4 + n) * 64 + lane) * 8];
                    acc[n] = __builtin_amdgcn_mfma_f32_16x16x32_f16(hf, bf, acc[n], 0, 0, 0);
                }
            }
            #pragma unroll
            for (int n = 0; n < 4; ++n) {
                float4v o = acc[n];
                #pragma unroll
                for (int r = 0; r < 4; ++r) o[r] += cbv[n];
                float* dst = a.zxbuf +
                    (((size_t)(xu * 4 + (t & 3)) * 32 + (cx * 4 + n)) * 8 + gmt) * 256 + lane * 4;
                st16cf(dst, o);
            }
            __syncthreads();
            if (tid == 0) st_flag_rel(&a.zxdone[myflag], t + 1);
        }
    }
}

// ---------------- FC: logits = [h_l2r ; gather(h_r2l)] @ W_fc + b_fc -------------
__global__ __launch_bounds__(NTHR) void fc_kernel(
    const h16* __restrict__ h2, const int* __restrict__ pad,
    const float* __restrict__ Wfc, const float* __restrict__ bfc,
    float* __restrict__ out)
{
    __shared__ float sA[64 * 68];
    __shared__ float sB[64 * 48];
    const int blk = blockIdx.x, tid = threadIdx.x;
    const int b = blk >> 2;
    const int j0 = (blk & 3) * 64;
    const int p = pad[b];
    const int rg = tid >> 4;
    const int c0 = (tid & 15) * 3;
    float acc[4][3] = {};

    for (int k0 = 0; k0 < 2 * Hdim; k0 += 64) {
        {
            int rr = tid >> 2;
            int kp = (tid & 3) * 16;
            int j = j0 + rr;
            const h16* src;
            if (k0 < Hdim) {
                src = h2 + (((size_t)0 * Tdim + j) * Bdim + b) * Hdim + k0 + kp;
            } else {
                int idx = (j < p) ? (p - j - 1) : j;
                src = h2 + (((size_t)1 * Tdim + idx) * Bdim + b) * Hdim + (k0 - Hdim) + kp;
            }
            union { uint4 u4; h16 h[8]; } w0, w1;
            w0.u4 = *(const uint4*)src;
            w1.u4 = *(const uint4*)(src + 8);
            #pragma unroll
            for (int i = 0; i < 8; ++i) {
                sA[rr * 68 + kp + i]     = (float)w0.h[i];
                sA[rr * 68 + kp + 8 + i] = (float)w1.h[i];
            }
        }
        for (int e = tid; e < 64 * 48; e += NTHR) {
            int kk = e / 48, c = e - kk * 48;
            sB[e] = (c < NC) ? Wfc[(k0 + kk) * NC + c] : 0.f;
        }
        __syncthreads();
        for (int kk = 0; kk < 64; ++kk) {
            float b0 = sB[kk * 48 + c0 + 0];
            float b1 = sB[kk * 48 + c0 + 1];
            float b2 = sB[kk * 48 + c0 + 2];
            #pragma unroll
            for (int i = 0; i < 4; ++i) {
                float av = sA[(rg * 4 + i) * 68 + kk];
                acc[i][0] += av * b0; acc[i][1] += av * b1; acc[i][2] += av * b2;
            }
        }
        __syncthreads();
    }
    #pragma unroll
    for (int i = 0; i < 4; ++i) {
        int r = blk * 64 + rg * 4 + i;
        #pragma unroll
        for (int jj = 0; jj < 3; ++jj) {
            int c = c0 + jj;
            if (c < NC) out[r * NC + c] = acc[i][jj] + bfc[c];
        }
    }
}

extern "C" void kernel_launch(void* const* d_in, const int* in_sizes, int n_in,
                              void* d_out, int out_size, void* d_ws, size_t ws_size,
                              hipStream_t stream) {
    const float* x      = (const float*)d_in[0];
    const float* rx     = (const float*)d_in[1];
    const int*   pad    = (const int*)d_in[2];
    const float* Wemb   = (const float*)d_in[4];
    const float* bemb   = (const float*)d_in[5];
    const float* Wx_l2r = (const float*)d_in[6];
    const float* bx_l2r = (const float*)d_in[7];
    const float* Wh_l2r = (const float*)d_in[8];
    const float* bh_l2r = (const float*)d_in[9];
    const float* Wx_r2l = (const float*)d_in[10];
    const float* bx_r2l = (const float*)d_in[11];
    const float* Wh_r2l = (const float*)d_in[12];
    const float* bh_r2l = (const float*)d_in[13];
    const float* lng    = (const float*)d_in[14];
    const float* lnb    = (const float*)d_in[15];
    const float* Wfc    = (const float*)d_in[16];
    const float* bfc    = (const float*)d_in[17];

    char* base = (char*)d_ws;
    size_t off = 0;
    auto alloc = [&](size_t bytes) { char* p = base + off; off += (bytes + 255) & ~(size_t)255; return p; };
    h16*   zx0f  = (h16*)  alloc((size_t)2 * Tdim * 32 * 8 * 64 * 4 * 2);      // 67 MB
    h16*   h2    = (h16*)  alloc((size_t)2 * Tdim * Bdim * Hdim * 2);          // 67 MB
    h16*   Wfrag = (h16*)  alloc((size_t)6 * 16 * 32768 * 2);                  // 6.3 MB
    h16*   W0f   = (h16*)  alloc((size_t)2 * 32 * 10 * 64 * 8 * 2);            // 0.66 MB
    h16*   zbuf  = (h16*)  alloc((size_t)6 * 4 * 65536 * 2);                   // 3.1 MB
    float* zxbuf = (float*)alloc((size_t)6 * 4 * 32 * 8 * 64 * 4 * 4);         // 6.3 MB
    float* W0    = (float*)alloc((size_t)2 * KXdim * Hdim * 4);
    float* cb    = (float*)alloc((size_t)2 * 3 * Hdim * 4);
    int*   zdoneH = (int*) alloc((size_t)6 * 32 * FPAD * 4);
    int*   zxdone = (int*) alloc((size_t)6 * 16 * FPAD * 4);

    prep1_kernel<<<(2 * KXdim * Hdim + 2 * 3 * Hdim) / NTHR, NTHR, 0, stream>>>(
        Wemb, bemb, Wx_l2r, bx_l2r, bh_l2r, Wx_r2l, bx_r2l, bh_r2l, W0, cb);

    pack_W_kernel<<<(6 * 16 * 32 * 2 * 64 * 8) / NTHR, NTHR, 0, stream>>>(
        W0, Wx_l2r, Wh_l2r, Wx_r2l, Wh_r2l, Wfrag);

    pack_W0f_kernel<<<(2 * 32 * 10 * 64 * 8) / NTHR, NTHR, 0, stream>>>(W0, W0f);

    zx0_kernel<<<1024, NTHR, 0, stream>>>(x, rx, W0f, cb, zx0f);

    zeroinit_kernel<<<(6 * 32 * FPAD + NTHR - 1) / NTHR, NTHR, 0, stream>>>(zdoneH, zxdone);

    PipeArgs a;
    a.Wfrag = Wfrag; a.zx0f = zx0f; a.cb = cb; a.lng = lng; a.lnb = lnb;
    a.zbuf = zbuf; a.zxbuf = zxbuf; a.h2 = h2;
    a.zdoneH = zdoneH; a.zxdone = zxdone;
    void* kargs[] = { &a };
    hipLaunchCooperativeKernel((void*)rnn_pipe, dim3(256), dim3(NTHR), kargs, 0, stream);

    fc_kernel<<<(Bdim * Tdim) / 64, NTHR, 0, stream>>>(h2, pad, Wfc, bfc, (float*)d_out);
}